// Round 14
// baseline (546.472 us; speedup 1.0000x reference)
//
#include <hip/hip_runtime.h>
#include <math.h>

#define B_ 16
#define N_ 2048
#define D_ 64
#define BT 64    // q-rows per workgroup (16 per wave)
#define MT 128   // k-cols per tile
#define DELTA 0.04f   // sound gap bound: > 2x worst-case bf16-split logit error

typedef const float __attribute__((address_space(1)))* gas_fp;  // global
typedef float __attribute__((address_space(3)))* las_fp;        // LDS
typedef __attribute__((ext_vector_type(8))) short bf8;          // 8 bf16 (4 VGPRs)
typedef __attribute__((ext_vector_type(4))) float f4;           // MFMA acc

// ---------------------------------------------------------------------------
// Kernel 0: detect mask element size (bool may arrive as int32 or uint8).
// Also zeroes the tie counter.
// ---------------------------------------------------------------------------
__global__ __launch_bounds__(256) void attn_detect(const unsigned int* __restrict__ mask,
                                                   int* __restrict__ flag,
                                                   int* __restrict__ tie_counter) {
    __shared__ int bad;
    if (threadIdx.x == 0) bad = 0;
    __syncthreads();
    unsigned int w = mask[threadIdx.x] | mask[threadIdx.x + 256] |
                     mask[threadIdx.x + 512] | mask[threadIdx.x + 768];
    if (w > 1u) bad = 1;
    __syncthreads();
    if (threadIdx.x == 0) { *flag = bad ? 1 : 4; *tie_counter = 0; }
}

// ---------------------------------------------------------------------------
// Kernel 0b: zero-fill attn — ONLY used on the fp32 fallback path (the MFMA
// kernel zero-fills its own slab in-line since R14).
// ---------------------------------------------------------------------------
__global__ __launch_bounds__(256) void attn_fill(float4* __restrict__ p, long long n4) {
    const float4 z = make_float4(0.f, 0.f, 0.f, 0.f);
    long long i = (long long)blockIdx.x * 256 + threadIdx.x;
    const long long stride = (long long)gridDim.x * 256;
    for (; i < n4; i += stride) p[i] = z;
}

// ---------------------------------------------------------------------------
// Kernel 0c: split q,k fp32 -> packed bf16 rows [hi(64) | lo(64)] (256 B/row).
// hi = RNE-bf16(x), lo = RNE-bf16(x - hi). All 4 cross terms in the MFMA;
// rows with top-2 gap < DELTA are recomputed exactly by attn_tiefix.
// ---------------------------------------------------------------------------
__device__ __forceinline__ unsigned short bf16rne(float f) {
    unsigned int u = __float_as_uint(f);
    return (unsigned short)((u + 0x7fffu + ((u >> 16) & 1u)) >> 16);
}
__global__ __launch_bounds__(256) void attn_convert(const float* __restrict__ q,
                                                    const float* __restrict__ k,
                                                    unsigned short* __restrict__ qx,
                                                    unsigned short* __restrict__ kx) {
    int gid  = blockIdx.x * 256 + threadIdx.x;     // 0 .. 262143
    int side = gid >> 17;                          // 0=q, 1=k
    int r    = (gid >> 2) & 32767;                 // row 0..32767
    int s    = gid & 3;                            // 16-elem segment
    const float* src = (side ? k : q) + (size_t)r * D_ + s * 16;
    unsigned short* dst = (side ? kx : qx) + (size_t)r * 128 + s * 16;
    #pragma unroll
    for (int i = 0; i < 16; ++i) {
        float f = src[i];
        unsigned short h = bf16rne(f);
        float fh = __uint_as_float(((unsigned int)h) << 16);
        unsigned short l = bf16rne(f - fh);
        dst[i]      = h;
        dst[64 + i] = l;
    }
}

// ---------------------------------------------------------------------------
// Kernel 1 (MFMA): R11/R13-proven structure + R14: in-line zero-fill of this
// block's 64x2048 attn slab (regular float4 stores, L2 full-line merge — NOT
// nontemporal [R2: 2.3x write amplification]). Ordering: final loop barrier
// emits s_waitcnt vmcnt(0) (compiler-verified) draining zeros before the
// epilogue's one-hot stores to the same block-exclusive rows.
// ---------------------------------------------------------------------------
__global__ __launch_bounds__(256)
void attn_mfma(const float* __restrict__ qx,
               const float* __restrict__ kx,
               const float* __restrict__ v,
               const void* __restrict__ maskp,
               float* __restrict__ attn,
               float* __restrict__ outp,
               const int* __restrict__ flagp,
               int* __restrict__ tie_counter,
               int* __restrict__ tie_recs) {
    const int flag = *flagp;
    const int tile = blockIdx.x;           // 512 blocks = 16 batches * 32 row-tiles
    const int b    = tile >> 5;
    const int n0   = (tile & 31) * BT;
    const int tid  = threadIdx.x;
    const int wv   = tid >> 6;             // wave 0..3
    const int ln   = tid & 63;
    const int l15  = ln & 15;
    const int quad = ln >> 4;              // 0..3
    const int lrow = quad;                 // DMA row within 4-row call
    const int lcs  = l15;                  // DMA chunk slot

    __shared__ float ks[2][MT * 64];       // 2 x 32 KB (bf16 data, 256B rows)
    __shared__ float qs[BT * 64];          // 16 KB

    const float* qbase  = qx + (size_t)(b * N_ + n0) * 64;   // 64 floats = 256 B row
    const float* kbatch = kx + (size_t)b * N_ * 64;

    #pragma unroll
    for (int it = 0; it < 4; ++it) {
        const int R   = wv * 16 + it * 4;
        const int row = R + lrow;
        const int cg  = lcs ^ (row & 15);
        __builtin_amdgcn_global_load_lds((gas_fp)(qbase + row * 64 + cg * 4),
                                         (las_fp)&qs[R * 64], 16, 0, 0);
    }
    #pragma unroll
    for (int it = 0; it < 8; ++it) {
        const int R   = wv * 32 + it * 4;
        const int row = R + lrow;
        const int cg  = lcs ^ (row & 15);
        __builtin_amdgcn_global_load_lds((gas_fp)(kbatch + row * 64 + cg * 4),
                                         (las_fp)&ks[0][R * 64], 16, 0, 0);
    }

    float lmax[4], lsec[4];
    int   lpos[4];
    #pragma unroll
    for (int r = 0; r < 4; ++r) { lmax[r] = -INFINITY; lsec[r] = -INFINITY; lpos[r] = 0; }

    const int* __restrict__ mask_i32 = (const int*)maskp;
    const unsigned char* __restrict__ mask_u8 = (const unsigned char*)maskp;
    const size_t rowbase = (size_t)b * N_ + n0;

    // zero-store geometry: thread covers rows (tid>>5)*8+i, cols (tid&31)*4
    const int zrow0 = (tid >> 5) * 8;
    const int zcol  = (tid & 31) * 4;

    __syncthreads();   // drain Q + K0 DMA

    bf8 afr[4];
    {
        const short* qsp = (const short*)qs + (wv * 16 + l15) * 128;
        #pragma unroll
        for (int c = 0; c < 4; ++c) {
            const int slot = (4 * c + quad) ^ l15;
            afr[c] = *(const bf8*)(qsp + slot * 8);
        }
    }

    #pragma unroll 1
    for (int mt = 0; mt < N_ / MT; ++mt) {
        const int m0  = mt * MT;
        const int cur = mt & 1;

        if (mt + 1 < N_ / MT) {
            const float* kb = kbatch + (size_t)(m0 + MT) * 64;
            #pragma unroll
            for (int it = 0; it < 8; ++it) {
                const int R   = wv * 32 + it * 4;
                const int row = R + lrow;
                const int cg  = lcs ^ (row & 15);
                __builtin_amdgcn_global_load_lds((gas_fp)(kb + row * 64 + cg * 4),
                                                 (las_fp)&ks[1 - cur][R * 64], 16, 0, 0);
            }
        }

        // ---- in-line zero-fill of this tile's attn slab (coalesced 1KB/inst) ----
        {
            const float4 z4 = make_float4(0.f, 0.f, 0.f, 0.f);
            #pragma unroll
            for (int i = 0; i < 8; ++i) {
                float* dst = attn + (rowbase + zrow0 + i) * N_ + m0 + zcol;
                *(float4*)dst = z4;
            }
        }

        unsigned char mk[8][4];
        if (flag == 4) {
            #pragma unroll
            for (int r = 0; r < 4; ++r) {
                const int* mrow = mask_i32 + (rowbase + wv * 16 + quad * 4 + r) * N_ + m0 + l15;
                #pragma unroll
                for (int ct = 0; ct < 8; ++ct)
                    mk[ct][r] = (unsigned char)(__builtin_nontemporal_load(mrow + ct * 16) != 0);
            }
        } else {
            #pragma unroll
            for (int r = 0; r < 4; ++r) {
                const unsigned char* mrow = mask_u8 + (rowbase + wv * 16 + quad * 4 + r) * N_ + m0 + l15;
                #pragma unroll
                for (int ct = 0; ct < 8; ++ct)
                    mk[ct][r] = (unsigned char)(__builtin_nontemporal_load(mrow + ct * 16) != 0);
            }
        }

        const short* ksb = (const short*)&ks[cur][0];
        f4 acc[8];
        #pragma unroll
        for (int ct = 0; ct < 8; ++ct) {
            const short* ksp = ksb + (ct * 16 + l15) * 128;
            bf8 bfr[4];
            #pragma unroll
            for (int c = 0; c < 4; ++c) {
                const int slot = (4 * c + quad) ^ l15;
                bfr[c] = *(const bf8*)(ksp + slot * 8);
            }
            f4 a = {0.f, 0.f, 0.f, 0.f};
            a = __builtin_amdgcn_mfma_f32_16x16x32_bf16(afr[2], bfr[2], a, 0, 0, 0); // lo.lo
            a = __builtin_amdgcn_mfma_f32_16x16x32_bf16(afr[3], bfr[3], a, 0, 0, 0);
            a = __builtin_amdgcn_mfma_f32_16x16x32_bf16(afr[0], bfr[2], a, 0, 0, 0); // hi.lo
            a = __builtin_amdgcn_mfma_f32_16x16x32_bf16(afr[1], bfr[3], a, 0, 0, 0);
            a = __builtin_amdgcn_mfma_f32_16x16x32_bf16(afr[2], bfr[0], a, 0, 0, 0); // lo.hi
            a = __builtin_amdgcn_mfma_f32_16x16x32_bf16(afr[3], bfr[1], a, 0, 0, 0);
            a = __builtin_amdgcn_mfma_f32_16x16x32_bf16(afr[0], bfr[0], a, 0, 0, 0); // hi.hi
            a = __builtin_amdgcn_mfma_f32_16x16x32_bf16(afr[1], bfr[1], a, 0, 0, 0);
            acc[ct] = a;
        }

        #pragma unroll
        for (int ct = 0; ct < 8; ++ct) {
            const int m = m0 + ct * 16 + l15;
            #pragma unroll
            for (int r = 0; r < 4; ++r) {
                float cand = mk[ct][r] ? -INFINITY : acc[ct][r];
                if (cand > lmax[r]) { lsec[r] = lmax[r]; lmax[r] = cand; lpos[r] = m; }
                else                lsec[r] = fmaxf(lsec[r], cand);
            }
        }

        __syncthreads();   // drain next-tile DMA + zero stores; protect buffer swap
    }

    #pragma unroll
    for (int r = 0; r < 4; ++r) {
        float m_ = lmax[r], s_ = lsec[r];
        int   p_ = lpos[r];
        #pragma unroll
        for (int off = 8; off >= 1; off >>= 1) {
            float om = __shfl_xor(m_, off);
            float os = __shfl_xor(s_, off);
            int   op = __shfl_xor(p_, off);
            if (om > m_)       { s_ = fmaxf(m_, os); m_ = om; p_ = op; }
            else if (om == m_) { s_ = m_; }           // tie across lanes -> gap 0
            else               { s_ = fmaxf(s_, om); }
        }
        const size_t row = rowbase + wv * 16 + quad * 4 + r;
        const bool safe = (m_ - s_ >= DELTA);   // NaN/-inf -> flagged
        if (l15 == 0) {
            if (safe) {
                attn[row * N_ + p_] = 1.0f;
            } else {
                int s = atomicAdd(tie_counter, 1);
                if (s < B_ * N_) tie_recs[s] = (int)row;
            }
        }
        float* orow = outp + row * D_;
        if (safe) {
            const float* vrow = v + ((size_t)b * N_ + p_) * D_;
            *(float4*)(orow + l15 * 4) = *(const float4*)(vrow + l15 * 4);
        } else {
            *(float4*)(orow + l15 * 4) = make_float4(0.f, 0.f, 0.f, 0.f);
        }
    }
}

// ---------------------------------------------------------------------------
// Kernel 2 (R13-proven): exact-fp32 fixup, GEMV-style. One block per flagged
// row; 8 chunks of 256 m; coalesced LDS staging + lane-local fmaf chains;
// cross-lane reduce ONCE per row.
// ---------------------------------------------------------------------------
__global__ __launch_bounds__(256) void attn_tiefix(const float* __restrict__ q,
                                                   const float* __restrict__ k,
                                                   const float* __restrict__ v,
                                                   const void* __restrict__ maskp,
                                                   float* __restrict__ attn,
                                                   float* __restrict__ outp,
                                                   const int* __restrict__ flagp,
                                                   const int* __restrict__ tie_counter,
                                                   const int* __restrict__ tie_recs) {
    const int ntie = *tie_counter;
    if (ntie == 0) return;
    const int flag = *flagp;
    const int tid  = threadIdx.x;
    const int wv   = tid >> 6;
    const int ln   = tid & 63;

    __shared__ float kt[256 * 68];   // 68 KB staged k-chunk (stride 68, 16B-aligned rows)
    __shared__ float us[N_];         // 8 KB per-m logits
    __shared__ float qsh[D_];
    __shared__ float wmax[4];
    __shared__ int tm[64];
    __shared__ int ntm;

    for (int idx = blockIdx.x; idx < ntie; idx += gridDim.x) {
        const int row = tie_recs[idx];
        const int b   = row >> 11;
        const float* kb = k + (size_t)b * N_ * D_;
        __syncthreads();             // protect LDS reuse across idx iterations
        if (tid == 0) ntm = 0;
        if (tid < 64) qsh[tid] = q[(size_t)row * D_ + tid];

        float tmax = -INFINITY;
        #pragma unroll 1
        for (int ch = 0; ch < 8; ++ch) {
            const int m0 = ch * 256;
            __syncthreads();         // prev chunk's readers done (also covers qsh)
            #pragma unroll
            for (int i = 0; i < 16; ++i) {
                const int fid = i * 256 + tid;
                const int r   = fid >> 4;
                const int c4  = (fid & 15) * 4;
                *(float4*)&kt[r * 68 + c4] = *(const float4*)(kb + (size_t)(m0 + r) * D_ + c4);
            }
            __syncthreads();
            const int m = m0 + tid;
            const float* kr = &kt[tid * 68];
            float u = 0.0f;
            #pragma unroll
            for (int d = 0; d < D_; ++d)
                u = fmaf(qsh[d], kr[d], u);
            bool msk = (flag == 4) ? (((const int*)maskp)[(size_t)row * N_ + m] != 0)
                                   : (((const unsigned char*)maskp)[(size_t)row * N_ + m] != 0);
            float t = msk ? -INFINITY : u;
            us[m] = t;
            tmax = fmaxf(tmax, t);
        }
        #pragma unroll
        for (int off = 32; off >= 1; off >>= 1)
            tmax = fmaxf(tmax, __shfl_xor(tmax, off));
        if (ln == 0) wmax[wv] = tmax;
        __syncthreads();
        const float gmax = fmaxf(fmaxf(wmax[0], wmax[1]), fmaxf(wmax[2], wmax[3]));
        for (int m = tid; m < N_; m += 256) {
            if (us[m] == gmax) { int s = atomicAdd(&ntm, 1); if (s < 64) tm[s] = m; }
        }
        __syncthreads();
        const int c = min(ntm, 64);
        const float inv = 1.0f / (float)ntm;
        if (tid < c) attn[(size_t)row * N_ + tm[tid]] = inv;
        if (tid < 64) {
            float sv = 0.0f;
            for (int t2 = 0; t2 < c; ++t2)
                sv += v[((size_t)b * N_ + tm[t2]) * D_ + tid];
            outp[(size_t)row * D_ + tid] = sv * inv;
        }
    }
}

// ---------------------------------------------------------------------------
// Kernel 1-alt (fp32 fallback if ws too small): R9's proven kernel.
// ---------------------------------------------------------------------------
__global__ __launch_bounds__(256)
void attn_fp32(const float* __restrict__ q,
               const float* __restrict__ k,
               const float* __restrict__ v,
               const void* __restrict__ maskp,
               float* __restrict__ attn,
               float* __restrict__ outp,
               const int* __restrict__ flagp,
               int* __restrict__ tie_counter,
               int* __restrict__ tie_recs) {
    const int flag = flagp ? *flagp : 4;
    const int tile = blockIdx.x;
    const int b    = tile >> 5;
    const int n0   = (tile & 31) * BT;
    const int tid  = threadIdx.x;
    const int tx   = tid & 31;
    const int ty   = tid >> 5;
    const int ty8  = ty * 8;
    const int wv   = tid >> 6;
    const int ln   = tid & 63;
    const int lrow = ln >> 4;
    const int lcs  = ln & 15;
    const int txl  = tx & 15;

    __shared__ float ks[2][MT * D_];
    __shared__ float qs[BT * D_];

    const float* qbase  = q + ((size_t)b * N_ + n0) * D_;
    const float* kbatch = k + (size_t)b * N_ * D_;

    #pragma unroll
    for (int it = 0; it < 4; ++it) {
        const int R   = wv * 16 + it * 4;
        const int row = R + lrow;
        __builtin_amdgcn_global_load_lds((gas_fp)(qbase + row * D_ + lcs * 4),
                                         (las_fp)&qs[R * D_], 16, 0, 0);
    }
    #pragma unroll
    for (int it = 0; it < 8; ++it) {
        const int R   = wv * 32 + it * 4;
        const int row = R + lrow;
        const int cg  = lcs ^ (row & 15);
        __builtin_amdgcn_global_load_lds((gas_fp)(kbatch + row * D_ + cg * 4),
                                         (las_fp)&ks[0][R * D_], 16, 0, 0);
    }

    float lmax[8];
    int   lcnt[8], lpos[8];
    #pragma unroll
    for (int i = 0; i < 8; ++i) { lmax[i] = -INFINITY; lcnt[i] = 0; lpos[i] = 0; }

    const int* __restrict__ mask_i32 = (const int*)maskp;
    const unsigned char* __restrict__ mask_u8 = (const unsigned char*)maskp;
    const size_t rowbase = (size_t)b * N_ + n0;

    __syncthreads();

    #pragma unroll 1
    for (int mt = 0; mt < N_ / MT; ++mt) {
        const int m0  = mt * MT;
        const int cur = mt & 1;
        if (mt + 1 < N_ / MT) {
            const float* kb = kbatch + (size_t)(m0 + MT) * D_;
            #pragma unroll
            for (int it = 0; it < 8; ++it) {
                const int R   = wv * 32 + it * 4;
                const int row = R + lrow;
                const int cg  = lcs ^ (row & 15);
                __builtin_amdgcn_global_load_lds((gas_fp)(kb + row * D_ + cg * 4),
                                                 (las_fp)&ks[1 - cur][R * D_], 16, 0, 0);
            }
        }
        unsigned char mk[8][4];
        if (flag == 4) {
            #pragma unroll
            for (int i = 0; i < 8; ++i) {
                const int* mrow = mask_i32 + (rowbase + ty8 + i) * N_ + m0;
                #pragma unroll
                for (int j = 0; j < 4; ++j)
                    mk[i][j] = (unsigned char)(__builtin_nontemporal_load(mrow + tx + 32 * j) != 0);
            }
        } else {
            #pragma unroll
            for (int i = 0; i < 8; ++i) {
                const unsigned char* mrow = mask_u8 + (rowbase + ty8 + i) * N_ + m0;
                #pragma unroll
                for (int j = 0; j < 4; ++j)
                    mk[i][j] = (unsigned char)(__builtin_nontemporal_load(mrow + tx + 32 * j) != 0);
            }
        }
        const float* ksb = &ks[cur][0];
        float acc[8][4];
        #pragma unroll
        for (int i = 0; i < 8; ++i)
            #pragma unroll
            for (int j = 0; j < 4; ++j) acc[i][j] = 0.0f;
        #pragma unroll 2
        for (int d = 0; d < D_; d += 4) {
            const int sw = (((d >> 2) ^ txl) << 2);
            float4 kv[4];
            #pragma unroll
            for (int j = 0; j < 4; ++j) kv[j] = *(const float4*)&ksb[(tx + 32 * j) * D_ + sw];
            #pragma unroll
            for (int i = 0; i < 8; ++i) {
                float4 qv = *(const float4*)&qs[(ty8 + i) * D_ + d];
                #pragma unroll
                for (int j = 0; j < 4; ++j) {
                    acc[i][j] = fmaf(qv.x, kv[j].x, acc[i][j]);
                    acc[i][j] = fmaf(qv.y, kv[j].y, acc[i][j]);
                    acc[i][j] = fmaf(qv.z, kv[j].z, acc[i][j]);
                    acc[i][j] = fmaf(qv.w, kv[j].w, acc[i][j]);
                }
            }
        }
        #pragma unroll
        for (int j = 0; j < 4; ++j) {
            int m = m0 + tx + 32 * j;
            #pragma unroll
            for (int i = 0; i < 8; ++i) {
                float cand = mk[i][j] ? -INFINITY : acc[i][j];
                if (cand > lmax[i])       { lmax[i] = cand; lcnt[i] = 1; lpos[i] = m; }
                else if (cand == lmax[i]) { lcnt[i]++; }
            }
        }
        __syncthreads();
    }

    #pragma unroll
    for (int i = 0; i < 8; ++i) {
        float m_ = lmax[i];
        int   c_ = lcnt[i];
        int   p_ = lpos[i];
        #pragma unroll
        for (int off = 16; off >= 1; off >>= 1) {
            float om = __shfl_xor(m_, off);
            int   oc = __shfl_xor(c_, off);
            int   op = __shfl_xor(p_, off);
            if (om > m_)       { m_ = om; c_ = oc; p_ = op; }
            else if (om == m_) { c_ += oc; p_ = min(p_, op); }
        }
        const size_t row = rowbase + ty8 + i;
        if (tx == 0) {
            if (c_ == 1) {
                attn[row * N_ + p_] = 1.0f;
            } else if (tie_recs) {
                int s = atomicAdd(tie_counter, 1);
                if (s < B_ * N_) tie_recs[s] = (int)row;
            } else {
                attn[row * N_ + p_] = 1.0f / (float)c_;
            }
        }
        float* orow = outp + row * D_;
        if (c_ == 1) {
            const float* vrow = v + ((size_t)b * N_ + p_) * D_;
            orow[tx]      = vrow[tx];
            orow[tx + 32] = vrow[tx + 32];
        } else {
            orow[tx]      = 0.0f;
            orow[tx + 32] = 0.0f;
        }
    }
}

extern "C" void kernel_launch(void* const* d_in, const int* in_sizes, int n_in,
                              void* d_out, int out_size, void* d_ws, size_t ws_size,
                              hipStream_t stream) {
    const float* q    = (const float*)d_in[0];
    const float* k    = (const float*)d_in[1];
    const float* v    = (const float*)d_in[2];
    const void*  mask = d_in[3];
    float* attn = (float*)d_out;
    float* outp = attn + (size_t)B_ * N_ * N_;

    // ws layout: [0] flag, [16] tiec, [64] tie rows (32768 ints);
    // [1MB] qx (8 MB packed bf16), [9MB] kx (8 MB).
    const size_t WS_QX = 1u << 20;
    const size_t WS_KX = WS_QX + (size_t)B_ * N_ * 128 * 2;
    const size_t need_mfma  = WS_KX + (size_t)B_ * N_ * 128 * 2;
    const size_t need_small = 64 + (size_t)(B_ * N_) * sizeof(int);
    const bool mfma_ok  = ws_size >= need_mfma;
    const bool full     = ws_size >= need_small;
    const bool haveflag = ws_size >= 32;
    int* flag = (int*)d_ws;
    int* tiec = (int*)((char*)d_ws + 16);
    int* tier = (int*)((char*)d_ws + 64);

    if (haveflag)
        attn_detect<<<1, 256, 0, stream>>>((const unsigned int*)mask, flag, tiec);

    if (mfma_ok && haveflag) {
        unsigned short* qx = (unsigned short*)((char*)d_ws + WS_QX);
        unsigned short* kx = (unsigned short*)((char*)d_ws + WS_KX);
        attn_convert<<<1024, 256, 0, stream>>>(q, k, qx, kx);
        attn_mfma<<<(B_ * N_) / BT, 256, 0, stream>>>(
            (const float*)qx, (const float*)kx, v, mask, attn, outp,
            flag, tiec, tier);
        attn_tiefix<<<512, 256, 0, stream>>>(q, k, v, mask, attn, outp, flag, tiec, tier);
    } else {
        attn_fill<<<2048, 256, 0, stream>>>((float4*)attn, (long long)B_ * N_ * N_ / 4);
        attn_fp32<<<(B_ * N_) / BT, 256, 0, stream>>>(
            q, k, v, mask, attn, outp,
            haveflag ? flag : nullptr,
            full ? tiec : nullptr,
            full ? tier : nullptr);
        if (full)
            attn_tiefix<<<512, 256, 0, stream>>>(q, k, v, mask, attn, outp, flag, tiec, tier);
    }
}

// Round 15
// 529.934 us; speedup vs baseline: 1.0312x; 1.0312x over previous
//
#include <hip/hip_runtime.h>
#include <math.h>

#define B_ 16
#define N_ 2048
#define D_ 64
#define BT 64    // q-rows per workgroup (16 per wave)
#define MT 128   // k-cols per tile
#define DELTA 0.04f   // sound gap bound: > 2x worst-case bf16-split logit error

typedef const float __attribute__((address_space(1)))* gas_fp;  // global
typedef float __attribute__((address_space(3)))* las_fp;        // LDS
typedef __attribute__((ext_vector_type(8))) short bf8;          // 8 bf16 (4 VGPRs)
typedef __attribute__((ext_vector_type(4))) float f4;           // MFMA acc

// ---------------------------------------------------------------------------
// Kernel 0b: zero-fill attn (268 MB) at HBM write BW. Separate kernel is the
// proven decomposition: R14's in-line fill inside attn_mfma cost +13 us
// (every loop barrier drains the stores: vmcnt(0) is all-or-nothing).
// ---------------------------------------------------------------------------
__global__ __launch_bounds__(256) void attn_fill(float4* __restrict__ p, long long n4) {
    const float4 z = make_float4(0.f, 0.f, 0.f, 0.f);
    long long i = (long long)blockIdx.x * 256 + threadIdx.x;
    const long long stride = (long long)gridDim.x * 256;
    for (; i < n4; i += stride) p[i] = z;
}

// ---------------------------------------------------------------------------
// Kernel 0c: split q,k fp32 -> packed bf16 rows [hi(64) | lo(64)] (256 B/row).
// hi = RNE-bf16(x), lo = RNE-bf16(x - hi). All 4 cross terms in the MFMA;
// rows with top-2 gap < DELTA are recomputed exactly by attn_tiefix.
// R15: block 0 also performs the mask-width detect (was its own kernel) and
// zeroes the tie counter — one less launch, stream order still guarantees
// flag is written before attn_mfma reads it.
// ---------------------------------------------------------------------------
__device__ __forceinline__ unsigned short bf16rne(float f) {
    unsigned int u = __float_as_uint(f);
    return (unsigned short)((u + 0x7fffu + ((u >> 16) & 1u)) >> 16);
}
__global__ __launch_bounds__(256) void attn_convert(const float* __restrict__ q,
                                                    const float* __restrict__ k,
                                                    unsigned short* __restrict__ qx,
                                                    unsigned short* __restrict__ kx,
                                                    const unsigned int* __restrict__ mask,
                                                    int* __restrict__ flag,
                                                    int* __restrict__ tie_counter) {
    if (blockIdx.x == 0) {
        // mask element-size detect: int32 0/1 -> all words in {0,1};
        // uint8 packing -> some word > 1.
        __shared__ int bad;
        if (threadIdx.x == 0) bad = 0;
        __syncthreads();
        unsigned int w = mask[threadIdx.x] | mask[threadIdx.x + 256] |
                         mask[threadIdx.x + 512] | mask[threadIdx.x + 768];
        if (w > 1u) bad = 1;
        __syncthreads();
        if (threadIdx.x == 0) { *flag = bad ? 1 : 4; *tie_counter = 0; }
    }
    int gid  = blockIdx.x * 256 + threadIdx.x;     // 0 .. 262143
    int side = gid >> 17;                          // 0=q, 1=k
    int r    = (gid >> 2) & 32767;                 // row 0..32767
    int s    = gid & 3;                            // 16-elem segment
    const float* src = (side ? k : q) + (size_t)r * D_ + s * 16;
    unsigned short* dst = (side ? kx : qx) + (size_t)r * 128 + s * 16;
    #pragma unroll
    for (int i = 0; i < 16; ++i) {
        float f = src[i];
        unsigned short h = bf16rne(f);
        float fh = __uint_as_float(((unsigned int)h) << 16);
        unsigned short l = bf16rne(f - fh);
        dst[i]      = h;
        dst[64 + i] = l;
    }
}

// ---------------------------------------------------------------------------
// Kernel 1 (MFMA): R11/R13-proven (absmax 0.0, ~150 us). 64 q-rows vs all
// 2048 k-cols per block; 8 col-tiles x 8 MFMA 16x16x32 bf16 = full
// (hi+lo)x(hi+lo); async-DMA XOR-swizzle double-buffered staging; second-max
// gap guard flags rows for exact recompute. NO occupancy attributes (all
// variants -> 68-84 VGPR cap -> spill [R3,R4,R6,R7]); NO in-line zero-fill
// (R14: barrier drains make it a net loss). LDS=80KB -> 2 blocks/CU.
// ---------------------------------------------------------------------------
__global__ __launch_bounds__(256)
void attn_mfma(const float* __restrict__ qx,
               const float* __restrict__ kx,
               const float* __restrict__ v,
               const void* __restrict__ maskp,
               float* __restrict__ attn,
               float* __restrict__ outp,
               const int* __restrict__ flagp,
               int* __restrict__ tie_counter,
               int* __restrict__ tie_recs) {
    const int flag = *flagp;
    const int tile = blockIdx.x;           // 512 blocks = 16 batches * 32 row-tiles
    const int b    = tile >> 5;
    const int n0   = (tile & 31) * BT;
    const int tid  = threadIdx.x;
    const int wv   = tid >> 6;             // wave 0..3
    const int ln   = tid & 63;
    const int l15  = ln & 15;
    const int quad = ln >> 4;              // 0..3
    const int lrow = quad;                 // DMA row within 4-row call
    const int lcs  = l15;                  // DMA chunk slot

    __shared__ float ks[2][MT * 64];       // 2 x 32 KB (bf16 data, 256B rows)
    __shared__ float qs[BT * 64];          // 16 KB

    const float* qbase  = qx + (size_t)(b * N_ + n0) * 64;   // 64 floats = 256 B row
    const float* kbatch = kx + (size_t)b * N_ * 64;

    #pragma unroll
    for (int it = 0; it < 4; ++it) {
        const int R   = wv * 16 + it * 4;
        const int row = R + lrow;
        const int cg  = lcs ^ (row & 15);
        __builtin_amdgcn_global_load_lds((gas_fp)(qbase + row * 64 + cg * 4),
                                         (las_fp)&qs[R * 64], 16, 0, 0);
    }
    #pragma unroll
    for (int it = 0; it < 8; ++it) {
        const int R   = wv * 32 + it * 4;
        const int row = R + lrow;
        const int cg  = lcs ^ (row & 15);
        __builtin_amdgcn_global_load_lds((gas_fp)(kbatch + row * 64 + cg * 4),
                                         (las_fp)&ks[0][R * 64], 16, 0, 0);
    }

    float lmax[4], lsec[4];
    int   lpos[4];
    #pragma unroll
    for (int r = 0; r < 4; ++r) { lmax[r] = -INFINITY; lsec[r] = -INFINITY; lpos[r] = 0; }

    const int* __restrict__ mask_i32 = (const int*)maskp;
    const unsigned char* __restrict__ mask_u8 = (const unsigned char*)maskp;
    const size_t rowbase = (size_t)b * N_ + n0;

    __syncthreads();   // drain Q + K0 DMA

    bf8 afr[4];
    {
        const short* qsp = (const short*)qs + (wv * 16 + l15) * 128;
        #pragma unroll
        for (int c = 0; c < 4; ++c) {
            const int slot = (4 * c + quad) ^ l15;
            afr[c] = *(const bf8*)(qsp + slot * 8);
        }
    }

    #pragma unroll 1
    for (int mt = 0; mt < N_ / MT; ++mt) {
        const int m0  = mt * MT;
        const int cur = mt & 1;

        if (mt + 1 < N_ / MT) {
            const float* kb = kbatch + (size_t)(m0 + MT) * 64;
            #pragma unroll
            for (int it = 0; it < 8; ++it) {
                const int R   = wv * 32 + it * 4;
                const int row = R + lrow;
                const int cg  = lcs ^ (row & 15);
                __builtin_amdgcn_global_load_lds((gas_fp)(kb + row * 64 + cg * 4),
                                                 (las_fp)&ks[1 - cur][R * 64], 16, 0, 0);
            }
        }

        unsigned char mk[8][4];
        if (flag == 4) {
            #pragma unroll
            for (int r = 0; r < 4; ++r) {
                const int* mrow = mask_i32 + (rowbase + wv * 16 + quad * 4 + r) * N_ + m0 + l15;
                #pragma unroll
                for (int ct = 0; ct < 8; ++ct)
                    mk[ct][r] = (unsigned char)(__builtin_nontemporal_load(mrow + ct * 16) != 0);
            }
        } else {
            #pragma unroll
            for (int r = 0; r < 4; ++r) {
                const unsigned char* mrow = mask_u8 + (rowbase + wv * 16 + quad * 4 + r) * N_ + m0 + l15;
                #pragma unroll
                for (int ct = 0; ct < 8; ++ct)
                    mk[ct][r] = (unsigned char)(__builtin_nontemporal_load(mrow + ct * 16) != 0);
            }
        }

        const short* ksb = (const short*)&ks[cur][0];
        f4 acc[8];
        #pragma unroll
        for (int ct = 0; ct < 8; ++ct) {
            const short* ksp = ksb + (ct * 16 + l15) * 128;
            bf8 bfr[4];
            #pragma unroll
            for (int c = 0; c < 4; ++c) {
                const int slot = (4 * c + quad) ^ l15;
                bfr[c] = *(const bf8*)(ksp + slot * 8);
            }
            f4 a = {0.f, 0.f, 0.f, 0.f};
            a = __builtin_amdgcn_mfma_f32_16x16x32_bf16(afr[2], bfr[2], a, 0, 0, 0); // lo.lo
            a = __builtin_amdgcn_mfma_f32_16x16x32_bf16(afr[3], bfr[3], a, 0, 0, 0);
            a = __builtin_amdgcn_mfma_f32_16x16x32_bf16(afr[0], bfr[2], a, 0, 0, 0); // hi.lo
            a = __builtin_amdgcn_mfma_f32_16x16x32_bf16(afr[1], bfr[3], a, 0, 0, 0);
            a = __builtin_amdgcn_mfma_f32_16x16x32_bf16(afr[2], bfr[0], a, 0, 0, 0); // lo.hi
            a = __builtin_amdgcn_mfma_f32_16x16x32_bf16(afr[3], bfr[1], a, 0, 0, 0);
            a = __builtin_amdgcn_mfma_f32_16x16x32_bf16(afr[0], bfr[0], a, 0, 0, 0); // hi.hi
            a = __builtin_amdgcn_mfma_f32_16x16x32_bf16(afr[1], bfr[1], a, 0, 0, 0);
            acc[ct] = a;
        }

        #pragma unroll
        for (int ct = 0; ct < 8; ++ct) {
            const int m = m0 + ct * 16 + l15;
            #pragma unroll
            for (int r = 0; r < 4; ++r) {
                float cand = mk[ct][r] ? -INFINITY : acc[ct][r];
                if (cand > lmax[r]) { lsec[r] = lmax[r]; lmax[r] = cand; lpos[r] = m; }
                else                lsec[r] = fmaxf(lsec[r], cand);
            }
        }

        __syncthreads();   // drain next-tile DMA; protect buffer swap
    }

    #pragma unroll
    for (int r = 0; r < 4; ++r) {
        float m_ = lmax[r], s_ = lsec[r];
        int   p_ = lpos[r];
        #pragma unroll
        for (int off = 8; off >= 1; off >>= 1) {
            float om = __shfl_xor(m_, off);
            float os = __shfl_xor(s_, off);
            int   op = __shfl_xor(p_, off);
            if (om > m_)       { s_ = fmaxf(m_, os); m_ = om; p_ = op; }
            else if (om == m_) { s_ = m_; }           // tie across lanes -> gap 0
            else               { s_ = fmaxf(s_, om); }
        }
        const size_t row = rowbase + wv * 16 + quad * 4 + r;
        const bool safe = (m_ - s_ >= DELTA);   // NaN/-inf -> flagged
        if (l15 == 0) {
            if (safe) {
                attn[row * N_ + p_] = 1.0f;
            } else {
                int s = atomicAdd(tie_counter, 1);
                if (s < B_ * N_) tie_recs[s] = (int)row;
            }
        }
        float* orow = outp + row * D_;
        if (safe) {
            const float* vrow = v + ((size_t)b * N_ + p_) * D_;
            *(float4*)(orow + l15 * 4) = *(const float4*)(vrow + l15 * 4);
        } else {
            *(float4*)(orow + l15 * 4) = make_float4(0.f, 0.f, 0.f, 0.f);
        }
    }
}

// ---------------------------------------------------------------------------
// Kernel 2 (R13-proven): exact-fp32 fixup, GEMV-style. One block per flagged
// row; 8 chunks of 256 m; coalesced LDS staging + lane-local fmaf chains;
// cross-lane reduce ONCE per row. (R11's per-lane row walk was uncoalesced:
// 173 us. R12's per-m shuffle butterfly was DS-latency-serial: 845 us.)
// ---------------------------------------------------------------------------
__global__ __launch_bounds__(256) void attn_tiefix(const float* __restrict__ q,
                                                   const float* __restrict__ k,
                                                   const float* __restrict__ v,
                                                   const void* __restrict__ maskp,
                                                   float* __restrict__ attn,
                                                   float* __restrict__ outp,
                                                   const int* __restrict__ flagp,
                                                   const int* __restrict__ tie_counter,
                                                   const int* __restrict__ tie_recs) {
    const int ntie = *tie_counter;
    if (ntie == 0) return;
    const int flag = *flagp;
    const int tid  = threadIdx.x;
    const int wv   = tid >> 6;
    const int ln   = tid & 63;

    __shared__ float kt[256 * 68];   // 68 KB staged k-chunk (stride 68, 16B-aligned rows)
    __shared__ float us[N_];         // 8 KB per-m logits
    __shared__ float qsh[D_];
    __shared__ float wmax[4];
    __shared__ int tm[64];
    __shared__ int ntm;

    for (int idx = blockIdx.x; idx < ntie; idx += gridDim.x) {
        const int row = tie_recs[idx];
        const int b   = row >> 11;
        const float* kb = k + (size_t)b * N_ * D_;
        __syncthreads();             // protect LDS reuse across idx iterations
        if (tid == 0) ntm = 0;
        if (tid < 64) qsh[tid] = q[(size_t)row * D_ + tid];

        float tmax = -INFINITY;
        #pragma unroll 1
        for (int ch = 0; ch < 8; ++ch) {
            const int m0 = ch * 256;
            __syncthreads();         // prev chunk's readers done (also covers qsh)
            #pragma unroll
            for (int i = 0; i < 16; ++i) {
                const int fid = i * 256 + tid;
                const int r   = fid >> 4;
                const int c4  = (fid & 15) * 4;
                *(float4*)&kt[r * 68 + c4] = *(const float4*)(kb + (size_t)(m0 + r) * D_ + c4);
            }
            __syncthreads();
            const int m = m0 + tid;
            const float* kr = &kt[tid * 68];
            float u = 0.0f;
            #pragma unroll
            for (int d = 0; d < D_; ++d)
                u = fmaf(qsh[d], kr[d], u);
            bool msk = (flag == 4) ? (((const int*)maskp)[(size_t)row * N_ + m] != 0)
                                   : (((const unsigned char*)maskp)[(size_t)row * N_ + m] != 0);
            float t = msk ? -INFINITY : u;
            us[m] = t;
            tmax = fmaxf(tmax, t);
        }
        #pragma unroll
        for (int off = 32; off >= 1; off >>= 1)
            tmax = fmaxf(tmax, __shfl_xor(tmax, off));
        if (ln == 0) wmax[wv] = tmax;
        __syncthreads();
        const float gmax = fmaxf(fmaxf(wmax[0], wmax[1]), fmaxf(wmax[2], wmax[3]));
        for (int m = tid; m < N_; m += 256) {
            if (us[m] == gmax) { int s = atomicAdd(&ntm, 1); if (s < 64) tm[s] = m; }
        }
        __syncthreads();
        const int c = min(ntm, 64);
        const float inv = 1.0f / (float)ntm;
        if (tid < c) attn[(size_t)row * N_ + tm[tid]] = inv;
        if (tid < 64) {
            float sv = 0.0f;
            for (int t2 = 0; t2 < c; ++t2)
                sv += v[((size_t)b * N_ + tm[t2]) * D_ + tid];
            outp[(size_t)row * D_ + tid] = sv * inv;
        }
    }
}

// ---------------------------------------------------------------------------
// Kernel 1-alt (fp32 fallback if ws too small): R9's proven kernel.
// ---------------------------------------------------------------------------
__global__ __launch_bounds__(256)
void attn_fp32(const float* __restrict__ q,
               const float* __restrict__ k,
               const float* __restrict__ v,
               const void* __restrict__ maskp,
               float* __restrict__ attn,
               float* __restrict__ outp,
               const int* __restrict__ flagp,
               int* __restrict__ tie_counter,
               int* __restrict__ tie_recs) {
    const int flag = flagp ? *flagp : 4;
    const int tile = blockIdx.x;
    const int b    = tile >> 5;
    const int n0   = (tile & 31) * BT;
    const int tid  = threadIdx.x;
    const int tx   = tid & 31;
    const int ty   = tid >> 5;
    const int ty8  = ty * 8;
    const int wv   = tid >> 6;
    const int ln   = tid & 63;
    const int lrow = ln >> 4;
    const int lcs  = ln & 15;
    const int txl  = tx & 15;

    __shared__ float ks[2][MT * D_];
    __shared__ float qs[BT * D_];

    const float* qbase  = q + ((size_t)b * N_ + n0) * D_;
    const float* kbatch = k + (size_t)b * N_ * D_;

    #pragma unroll
    for (int it = 0; it < 4; ++it) {
        const int R   = wv * 16 + it * 4;
        const int row = R + lrow;
        __builtin_amdgcn_global_load_lds((gas_fp)(qbase + row * D_ + lcs * 4),
                                         (las_fp)&qs[R * D_], 16, 0, 0);
    }
    #pragma unroll
    for (int it = 0; it < 8; ++it) {
        const int R   = wv * 32 + it * 4;
        const int row = R + lrow;
        const int cg  = lcs ^ (row & 15);
        __builtin_amdgcn_global_load_lds((gas_fp)(kbatch + row * D_ + cg * 4),
                                         (las_fp)&ks[0][R * D_], 16, 0, 0);
    }

    float lmax[8];
    int   lcnt[8], lpos[8];
    #pragma unroll
    for (int i = 0; i < 8; ++i) { lmax[i] = -INFINITY; lcnt[i] = 0; lpos[i] = 0; }

    const int* __restrict__ mask_i32 = (const int*)maskp;
    const unsigned char* __restrict__ mask_u8 = (const unsigned char*)maskp;
    const size_t rowbase = (size_t)b * N_ + n0;

    __syncthreads();

    #pragma unroll 1
    for (int mt = 0; mt < N_ / MT; ++mt) {
        const int m0  = mt * MT;
        const int cur = mt & 1;
        if (mt + 1 < N_ / MT) {
            const float* kb = kbatch + (size_t)(m0 + MT) * D_;
            #pragma unroll
            for (int it = 0; it < 8; ++it) {
                const int R   = wv * 32 + it * 4;
                const int row = R + lrow;
                const int cg  = lcs ^ (row & 15);
                __builtin_amdgcn_global_load_lds((gas_fp)(kb + row * D_ + cg * 4),
                                                 (las_fp)&ks[1 - cur][R * D_], 16, 0, 0);
            }
        }
        unsigned char mk[8][4];
        if (flag == 4) {
            #pragma unroll
            for (int i = 0; i < 8; ++i) {
                const int* mrow = mask_i32 + (rowbase + ty8 + i) * N_ + m0;
                #pragma unroll
                for (int j = 0; j < 4; ++j)
                    mk[i][j] = (unsigned char)(__builtin_nontemporal_load(mrow + tx + 32 * j) != 0);
            }
        } else {
            #pragma unroll
            for (int i = 0; i < 8; ++i) {
                const unsigned char* mrow = mask_u8 + (rowbase + ty8 + i) * N_ + m0;
                #pragma unroll
                for (int j = 0; j < 4; ++j)
                    mk[i][j] = (unsigned char)(__builtin_nontemporal_load(mrow + tx + 32 * j) != 0);
            }
        }
        const float* ksb = &ks[cur][0];
        float acc[8][4];
        #pragma unroll
        for (int i = 0; i < 8; ++i)
            #pragma unroll
            for (int j = 0; j < 4; ++j) acc[i][j] = 0.0f;
        #pragma unroll 2
        for (int d = 0; d < D_; d += 4) {
            const int sw = (((d >> 2) ^ txl) << 2);
            float4 kv[4];
            #pragma unroll
            for (int j = 0; j < 4; ++j) kv[j] = *(const float4*)&ksb[(tx + 32 * j) * D_ + sw];
            #pragma unroll
            for (int i = 0; i < 8; ++i) {
                float4 qv = *(const float4*)&qs[(ty8 + i) * D_ + d];
                #pragma unroll
                for (int j = 0; j < 4; ++j) {
                    acc[i][j] = fmaf(qv.x, kv[j].x, acc[i][j]);
                    acc[i][j] = fmaf(qv.y, kv[j].y, acc[i][j]);
                    acc[i][j] = fmaf(qv.z, kv[j].z, acc[i][j]);
                    acc[i][j] = fmaf(qv.w, kv[j].w, acc[i][j]);
                }
            }
        }
        #pragma unroll
        for (int j = 0; j < 4; ++j) {
            int m = m0 + tx + 32 * j;
            #pragma unroll
            for (int i = 0; i < 8; ++i) {
                float cand = mk[i][j] ? -INFINITY : acc[i][j];
                if (cand > lmax[i])       { lmax[i] = cand; lcnt[i] = 1; lpos[i] = m; }
                else if (cand == lmax[i]) { lcnt[i]++; }
            }
        }
        __syncthreads();
    }

    #pragma unroll
    for (int i = 0; i < 8; ++i) {
        float m_ = lmax[i];
        int   c_ = lcnt[i];
        int   p_ = lpos[i];
        #pragma unroll
        for (int off = 16; off >= 1; off >>= 1) {
            float om = __shfl_xor(m_, off);
            int   oc = __shfl_xor(c_, off);
            int   op = __shfl_xor(p_, off);
            if (om > m_)       { m_ = om; c_ = oc; p_ = op; }
            else if (om == m_) { c_ += oc; p_ = min(p_, op); }
        }
        const size_t row = rowbase + ty8 + i;
        if (tx == 0) {
            if (c_ == 1) {
                attn[row * N_ + p_] = 1.0f;
            } else if (tie_recs) {
                int s = atomicAdd(tie_counter, 1);
                if (s < B_ * N_) tie_recs[s] = (int)row;
            } else {
                attn[row * N_ + p_] = 1.0f / (float)c_;
            }
        }
        float* orow = outp + row * D_;
        if (c_ == 1) {
            const float* vrow = v + ((size_t)b * N_ + p_) * D_;
            orow[tx]      = vrow[tx];
            orow[tx + 32] = vrow[tx + 32];
        } else {
            orow[tx]      = 0.0f;
            orow[tx + 32] = 0.0f;
        }
    }
}

// small standalone detect for the fallback path only
__global__ __launch_bounds__(256) void attn_detect(const unsigned int* __restrict__ mask,
                                                   int* __restrict__ flag,
                                                   int* __restrict__ tie_counter) {
    __shared__ int bad;
    if (threadIdx.x == 0) bad = 0;
    __syncthreads();
    unsigned int w = mask[threadIdx.x] | mask[threadIdx.x + 256] |
                     mask[threadIdx.x + 512] | mask[threadIdx.x + 768];
    if (w > 1u) bad = 1;
    __syncthreads();
    if (threadIdx.x == 0) { *flag = bad ? 1 : 4; *tie_counter = 0; }
}

extern "C" void kernel_launch(void* const* d_in, const int* in_sizes, int n_in,
                              void* d_out, int out_size, void* d_ws, size_t ws_size,
                              hipStream_t stream) {
    const float* q    = (const float*)d_in[0];
    const float* k    = (const float*)d_in[1];
    const float* v    = (const float*)d_in[2];
    const void*  mask = d_in[3];
    float* attn = (float*)d_out;
    float* outp = attn + (size_t)B_ * N_ * N_;

    // ws layout: [0] flag, [16] tiec, [64] tie rows (32768 ints);
    // [1MB] qx (8 MB packed bf16), [9MB] kx (8 MB).
    const size_t WS_QX = 1u << 20;
    const size_t WS_KX = WS_QX + (size_t)B_ * N_ * 128 * 2;
    const size_t need_mfma  = WS_KX + (size_t)B_ * N_ * 128 * 2;
    const size_t need_small = 64 + (size_t)(B_ * N_) * sizeof(int);
    const bool mfma_ok  = ws_size >= need_mfma;
    const bool full     = ws_size >= need_small;
    const bool haveflag = ws_size >= 32;
    int* flag = (int*)d_ws;
    int* tiec = (int*)((char*)d_ws + 16);
    int* tier = (int*)((char*)d_ws + 64);

    if (mfma_ok && haveflag) {
        unsigned short* qx = (unsigned short*)((char*)d_ws + WS_QX);
        unsigned short* kx = (unsigned short*)((char*)d_ws + WS_KX);
        attn_fill<<<2048, 256, 0, stream>>>((float4*)attn, (long long)B_ * N_ * N_ / 4);
        attn_convert<<<1024, 256, 0, stream>>>(q, k, qx, kx,
                                               (const unsigned int*)mask, flag, tiec);
        attn_mfma<<<(B_ * N_) / BT, 256, 0, stream>>>(
            (const float*)qx, (const float*)kx, v, mask, attn, outp,
            flag, tiec, tier);
        attn_tiefix<<<512, 256, 0, stream>>>(q, k, v, mask, attn, outp, flag, tiec, tier);
    } else {
        attn_fill<<<2048, 256, 0, stream>>>((float4*)attn, (long long)B_ * N_ * N_ / 4);
        if (haveflag)
            attn_detect<<<1, 256, 0, stream>>>((const unsigned int*)mask, flag, tiec);
        attn_fp32<<<(B_ * N_) / BT, 256, 0, stream>>>(
            q, k, v, mask, attn, outp,
            haveflag ? flag : nullptr,
            full ? tiec : nullptr,
            full ? tier : nullptr);
        if (full)
            attn_tiefix<<<512, 256, 0, stream>>>(q, k, v, mask, attn, outp, flag, tiec, tier);
    }
}